// Round 3
// baseline (152.779 us; speedup 1.0000x reference)
//
#include <hip/hip_runtime.h>

#define NN 50000
#define NE 800000
#define KF 256
#define MF 64

#define NBK 782      // node buckets of 64: ceil(50000/64)
#define SB 196       // scatter blocks (4x prev parallelism on the tail branch)
#define EPB 4096     // edges per scatter block (196*4096 >= 800000)
#define EPT 4        // edges per thread
#define CAP 1536     // fixed slots per bucket (mean 1024 + ~16 sigma)
#define GEMMB 196    // gemm blocks: each does 256 rows
#define OVF_CAP 4096 // overflow list capacity (never used in practice)

typedef __attribute__((ext_vector_type(8))) short short8;
typedef __attribute__((ext_vector_type(4))) float f32x4;

static __device__ __forceinline__ unsigned short f2bf(float x) {
  unsigned int u = __float_as_uint(x);
  u += 0x7FFF + ((u >> 16) & 1);  // round-nearest-even
  return (unsigned short)(u >> 16);
}
static __device__ __forceinline__ float bf2f(unsigned short u) {
  return __uint_as_float(((unsigned int)u) << 16);
}

// LDS union: GEMM branch's 32 KB W-table overlays the scatter branch's
// sort workspace (16 KB sorted list + 3x782 ints) -> kernel LDS stays 32 KB.
union SMem1 {
  unsigned short wt[16384];  // GEMM: B-fragment table (32 KB)
  struct {
    int sorted[EPB];  // block-local bucket-sorted edges (16 KB)
    int hh[NBK];      // histogram -> inclusive scan
    int bb[NBK];      // placement cursor (starts at exclusive scan)
    int gbase[NBK];   // reserved base in the bucket's global region
  } sc;
};

// ---- Kernel 1: edge scatter w/ local sort (blocks 0..SB-1) + GEMM (SB..) ----
__global__ __launch_bounds__(1024) void scatter_gemm(
    const int* __restrict__ src, const int* __restrict__ dst,
    int* __restrict__ gCur, int* __restrict__ gOvf,
    unsigned int* __restrict__ ovf, int* __restrict__ eidx,
    const float* __restrict__ h, const float* __restrict__ W,
    const float* __restrict__ norm, unsigned short* __restrict__ hwb) {
  __shared__ SMem1 u;
  const int t = threadIdx.x;

  if (blockIdx.x >= SB) {  // ---- GEMM branch: 4 x 64-row tiles ----
    // prepack W -> LDS (layout: f = k0i*256 + nt*64 + quad*16 + m)
    for (int f = t; f < 2048; f += 1024) {
      const int m = f & 15;
      const int quad = (f >> 4) & 3;
      const int nt = (f >> 6) & 3;
      const int k0i = f >> 8;
      const int n = nt * 16 + m;
      const int kb = k0i * 32 + quad * 8;
      short8 p;
#pragma unroll
      for (int j = 0; j < 8; ++j) p[j] = (short)f2bf(W[(kb + j) * MF + n]);
      *(short8*)(u.wt + (size_t)f * 8) = p;
    }

    const int sub = t >> 8;        // 0..3
    const int tt = t & 255;
    const int lane = tt & 63;
    const int wv = tt >> 6;        // 0..3
    const int m = lane & 15;
    const int quad = lane >> 4;    // 0..3
    const int row0 = (blockIdx.x - SB) * 256 + sub * 64;
    const int arow = row0 + wv * 16 + m;
    const int rowc = (arow < NN) ? arow : (NN - 1);  // clamp; store guarded
    const float4* ap = (const float4*)(h + (size_t)rowc * KF + quad * 8);

    float4 a[16];
#pragma unroll
    for (int k = 0; k < 8; ++k) {
      a[2 * k] = ap[k * 8];
      a[2 * k + 1] = ap[k * 8 + 1];
    }
    __builtin_amdgcn_sched_barrier(0);  // all 16 A-loads issue first

    short8 af[8];
#pragma unroll
    for (int k = 0; k < 8; ++k) {
      const float4 a0 = a[2 * k];
      const float4 a1 = a[2 * k + 1];
      af[k][0] = (short)f2bf(a0.x); af[k][1] = (short)f2bf(a0.y);
      af[k][2] = (short)f2bf(a0.z); af[k][3] = (short)f2bf(a0.w);
      af[k][4] = (short)f2bf(a1.x); af[k][5] = (short)f2bf(a1.y);
      af[k][6] = (short)f2bf(a1.z); af[k][7] = (short)f2bf(a1.w);
    }
    __syncthreads();  // wt ready

    f32x4 acc[4];
#pragma unroll
    for (int i = 0; i < 4; ++i) acc[i] = (f32x4){0.f, 0.f, 0.f, 0.f};

    const short8* wp = (const short8*)u.wt;
#pragma unroll
    for (int k0i = 0; k0i < 8; ++k0i) {
      const short8* wk = wp + k0i * 256 + lane;
#pragma unroll
      for (int nt = 0; nt < 4; ++nt) {
        const short8 bf = wk[nt * 64];  // ds_read_b128, conflict-free
        acc[nt] = __builtin_amdgcn_mfma_f32_16x16x32_bf16(af[k0i], bf, acc[nt], 0, 0, 0);
      }
    }

    const int gm0 = row0 + wv * 16 + quad * 4;
    float nrm[4];
#pragma unroll
    for (int r = 0; r < 4; ++r) nrm[r] = (gm0 + r < NN) ? norm[gm0 + r] : 0.f;
#pragma unroll
    for (int nt = 0; nt < 4; ++nt) {
#pragma unroll
      for (int r = 0; r < 4; ++r) {
        const int gm = gm0 + r;
        if (gm < NN) hwb[(size_t)gm * MF + nt * 16 + m] = f2bf(acc[nt][r] * nrm[r]);
      }
    }
    return;
  }

  // ---- scatter branch: local counting sort -> coalesced bucket writes ----
  const int base = (int)blockIdx.x * EPB;
  unsigned int ev[EPT];
#pragma unroll
  for (int i = 0; i < EPT; ++i) {
    const int e = base + i * 1024 + t;
    ev[i] = (e < NE) ? (((unsigned)src[e] << 16) | (unsigned)dst[e])
                     : 0xFFFFFFFFu;  // sentinel
  }
  for (int i = t; i < NBK; i += 1024) u.sc.hh[i] = 0;
  __syncthreads();
#pragma unroll
  for (int i = 0; i < EPT; ++i)
    if (ev[i] != 0xFFFFFFFFu) atomicAdd(&u.sc.hh[(ev[i] & 0xFFFFu) >> 6], 1);
  __syncthreads();
  // in-place Hillis-Steele inclusive scan over 782 counts
  for (int off = 1; off < 1024; off <<= 1) {
    int a = 0;
    if (t >= off && t < NBK) a = u.sc.hh[t - off];
    __syncthreads();
    if (t < NBK) u.sc.hh[t] += a;
    __syncthreads();
  }
  if (t < NBK) {
    const int incl = u.sc.hh[t];
    const int excl = t ? u.sc.hh[t - 1] : 0;
    u.sc.bb[t] = excl;
    const int c = incl - excl;
    if (c) u.sc.gbase[t] = atomicAdd(&gCur[t], c);  // chunk reservation
  }
  __syncthreads();
#pragma unroll
  for (int i = 0; i < EPT; ++i) {
    const unsigned v = ev[i];
    if (v != 0xFFFFFFFFu) {
      const int d = (int)(v & 0xFFFFu);
      const int p = atomicAdd(&u.sc.bb[d >> 6], 1);
      u.sc.sorted[p] = (int)((v >> 16) << 6) | (d & 63);
    }
  }
  __syncthreads();
  // coalesced write-out: each wave drains its buckets as contiguous runs
  const int wv = t >> 6;
  const int lane = t & 63;
  for (int b = wv; b < NBK; b += 16) {
    const int incl = __builtin_amdgcn_readfirstlane(u.sc.hh[b]);
    const int excl = __builtin_amdgcn_readfirstlane(b ? u.sc.hh[b - 1] : 0);
    const int len = incl - excl;
    if (len == 0) continue;
    const int gb = __builtin_amdgcn_readfirstlane(u.sc.gbase[b]);
    for (int off = lane; off < len; off += 64) {
      const int val = u.sc.sorted[excl + off];
      const int gp = gb + off;
      if (gp < CAP) {
        eidx[(size_t)b * CAP + gp] = val;
      } else {  // statistically unreachable; kept for correctness
        const int o = atomicAdd(gOvf, 1);
        if (o < OVF_CAP)
          ovf[o] = ((unsigned)(val >> 6) << 16) | (unsigned)(b * 64 + (val & 63));
      }
    }
  }
}

// ---- Kernel 2: per-bucket counting sort (LDS) + 4-node interleaved gather ----
// Wave's 4 nodes processed CONCURRENTLY: batches of 4 rows x 4 nodes = 16
// loads in flight (bounds are wave-uniform scalars -> no divergence).
// launch_bounds(1024,8): cap VGPR at 64 -> 2 blocks/CU, sort phase of one
// block hides under the gather phase of the other.
__global__ __launch_bounds__(1024, 8) void sort_gather(
    const int* __restrict__ gCur, const int* __restrict__ gOvf,
    const unsigned int* __restrict__ ovf, const int* __restrict__ eidx,
    const unsigned short* __restrict__ hwb, const float* __restrict__ norm,
    const float* __restrict__ bias, float* __restrict__ out) {
  __shared__ int hcnt[64];   // histogram -> node end (after scan)
  __shared__ int sBeg[64];   // node start (local)
  __shared__ int sCur[64];
  __shared__ int sE[CAP];
  const int t = threadIdx.x;
  const int g = blockIdx.x;
  int cnt = gCur[g];
  cnt = (cnt < CAP) ? cnt : CAP;  // excess (never happens) is in ovf list
  cnt = __builtin_amdgcn_readfirstlane(cnt);
  const int* ep = eidx + (size_t)g * CAP;
  if (t < 64) hcnt[t] = 0;
  __syncthreads();
  // hist pass; stash edge words in regs (cnt <= 1536 -> <= 2 per thread)
  int v0 = -1, v1 = -1;
  if (t < cnt) {
    v0 = ep[t];
    atomicAdd(&hcnt[v0 & 63], 1);
  }
  if (t + 1024 < cnt) {
    v1 = ep[t + 1024];
    atomicAdd(&hcnt[v1 & 63], 1);
  }
  __syncthreads();
  if (t < 64) {  // wave 0: exclusive scan of 64 counts
    const int v = hcnt[t];
    int incl = v;
#pragma unroll
    for (int off = 1; off < 64; off <<= 1) {
      const int uu = __shfl_up(incl, off, 64);
      if (t >= off) incl += uu;
    }
    sBeg[t] = incl - v;
    sCur[t] = incl - v;
    hcnt[t] = incl;  // end
  }
  __syncthreads();
  if (v0 >= 0) sE[atomicAdd(&sCur[v0 & 63], 1)] = v0 >> 6;
  if (v1 >= 0) sE[atomicAdd(&sCur[v1 & 63], 1)] = v1 >> 6;
  __syncthreads();

  const int lane = t & 63;
  const int wv = t >> 6;  // 0..15; wave handles nodes wv, wv+16, wv+32, wv+48
  const float bi = bias[lane];
  const int novf = __builtin_amdgcn_readfirstlane(*gOvf);  // 0 in practice

  int sI[4], eI[4];
  float ac[4];
#pragma unroll
  for (int r = 0; r < 4; ++r) {
    const int nl = wv + 16 * r;
    sI[r] = __builtin_amdgcn_readfirstlane(sBeg[nl]);
    eI[r] = __builtin_amdgcn_readfirstlane(hcnt[nl]);
    ac[r] = 0.f;
  }
  // interleaved batches: 4 rows x up-to-4 nodes = 16 loads in flight
  while (true) {
    int msk = 0;
    unsigned short x[4][4];
#pragma unroll
    for (int r = 0; r < 4; ++r) {
      if (sI[r] + 4 <= eI[r]) {
        msk |= 1 << r;
        const int i0 = sI[r];
        const int s0 = sE[i0], s1 = sE[i0 + 1], s2 = sE[i0 + 2], s3 = sE[i0 + 3];
        x[r][0] = hwb[(size_t)s0 * MF + lane];
        x[r][1] = hwb[(size_t)s1 * MF + lane];
        x[r][2] = hwb[(size_t)s2 * MF + lane];
        x[r][3] = hwb[(size_t)s3 * MF + lane];
      }
    }
    if (!msk) break;
    __builtin_amdgcn_sched_barrier(0);  // keep all loads ahead of uses
#pragma unroll
    for (int r = 0; r < 4; ++r) {
      if (msk & (1 << r)) {
        ac[r] += (bf2f(x[r][0]) + bf2f(x[r][1])) + (bf2f(x[r][2]) + bf2f(x[r][3]));
        sI[r] += 4;
      }
    }
  }
  // 4-node-wide tail, one row per node per step
  while (true) {
    int msk = 0;
    unsigned short y[4];
#pragma unroll
    for (int r = 0; r < 4; ++r) {
      if (sI[r] < eI[r]) {
        msk |= 1 << r;
        y[r] = hwb[(size_t)sE[sI[r]] * MF + lane];
      }
    }
    if (!msk) break;
#pragma unroll
    for (int r = 0; r < 4; ++r) {
      if (msk & (1 << r)) {
        ac[r] += bf2f(y[r]);
        sI[r] += 1;
      }
    }
  }

#pragma unroll
  for (int r = 0; r < 4; ++r) {
    const int nl = wv + 16 * r;
    const int vtx = (g << 6) + nl;
    if (vtx >= NN) continue;
    float acc = ac[r];
    if (novf > 0) {  // cold path, wave-uniform skip
      const int nn = (novf < OVF_CAP) ? novf : OVF_CAP;
      for (int ii = 0; ii < nn; ++ii) {
        const unsigned v = ovf[ii];
        if ((int)(v & 0xFFFFu) == vtx)
          acc += bf2f(hwb[(size_t)(v >> 16) * MF + lane]);
      }
    }
    const float o = acc * norm[vtx] + bi;
    out[(size_t)vtx * MF + lane] = fmaxf(o, 0.f);
  }
}

extern "C" void kernel_launch(void* const* d_in, const int* in_sizes, int n_in,
                              void* d_out, int out_size, void* d_ws, size_t ws_size,
                              hipStream_t stream) {
  const float* h = (const float*)d_in[0];
  const float* norm = (const float*)d_in[1];
  const float* W = (const float*)d_in[2];
  const float* bias = (const float*)d_in[3];
  const int* src = (const int*)d_in[4];
  const int* dst = (const int*)d_in[5];
  float* out = (float*)d_out;

  unsigned short* hwb = (unsigned short*)d_ws;            // NN*MF bf16 (6.4 MB)
  int* gCur = (int*)(hwb + (size_t)NN * MF);              // NBK bucket cursors
  int* gOvf = gCur + NBK;                                 // overflow counter
  unsigned int* ovf = (unsigned int*)(gOvf + 1);          // OVF_CAP entries
  int* eidx = (int*)(ovf + OVF_CAP);                      // NBK*CAP (4.8 MB)
  const size_t need = (size_t)NN * MF * 2 +
                      ((size_t)NBK + 1 + OVF_CAP + (size_t)NBK * CAP) * 4;
  if (ws_size < need) return;

  hipMemsetAsync(gCur, 0, (NBK + 1) * sizeof(int), stream);  // 3 KB
  scatter_gemm<<<SB + GEMMB, 1024, 0, stream>>>(src, dst, gCur, gOvf, ovf,
                                                eidx, h, W, norm, hwb);
  sort_gather<<<NBK, 1024, 0, stream>>>(gCur, gOvf, ovf, eidx, hwb, norm, bias,
                                        out);
}

// Round 6
// 134.679 us; speedup vs baseline: 1.1344x; 1.1344x over previous
//
#include <hip/hip_runtime.h>

#define NN 50000
#define NE 800000
#define KF 256
#define MF 64

#define NBK 782      // node buckets of 64: ceil(50000/64)
#define SB 49        // scatter blocks (proven co-residency with GEMM)
#define EPB 16384    // edges per scatter block (49*16384 >= 800000)
#define CAP 1536     // fixed slots per bucket (mean 1024 + ~16 sigma)
#define GEMMB 196    // gemm blocks: each does 256 rows
#define OVF_CAP 4096 // overflow list capacity (never used in practice)

typedef __attribute__((ext_vector_type(8))) short short8;
typedef __attribute__((ext_vector_type(4))) float f32x4;

static __device__ __forceinline__ unsigned short f2bf(float x) {
  unsigned int u = __float_as_uint(x);
  u += 0x7FFF + ((u >> 16) & 1);  // round-nearest-even
  return (unsigned short)(u >> 16);
}
static __device__ __forceinline__ float bf2f(unsigned short u) {
  return __uint_as_float(((unsigned int)u) << 16);
}

// ---- Kernel 1: fused edge scatter (blocks 0..SB-1) + MFMA GEMM (SB..) ----
// Byte-identical to the round-2 passing version (134.7 us).
__global__ __launch_bounds__(1024) void scatter_gemm(
    const int* __restrict__ src, const int* __restrict__ dst,
    int* __restrict__ gCur, int* __restrict__ gOvf,
    unsigned int* __restrict__ ovf, int* __restrict__ eidx,
    const float* __restrict__ h, const float* __restrict__ W,
    const float* __restrict__ norm, unsigned short* __restrict__ hwb) {
  const int t = threadIdx.x;

  if (blockIdx.x >= SB) {  // ---- GEMM branch: 4 x 64-row tiles ----
    __shared__ unsigned short wt[16384];  // 32 KB B-fragment table
    // prepack W -> LDS (layout: f = k0i*256 + nt*64 + quad*16 + m)
    for (int f = t; f < 2048; f += 1024) {
      const int m = f & 15;
      const int quad = (f >> 4) & 3;
      const int nt = (f >> 6) & 3;
      const int k0i = f >> 8;
      const int n = nt * 16 + m;
      const int kb = k0i * 32 + quad * 8;
      short8 p;
#pragma unroll
      for (int j = 0; j < 8; ++j) p[j] = (short)f2bf(W[(kb + j) * MF + n]);
      *(short8*)(wt + (size_t)f * 8) = p;
    }

    const int sub = t >> 8;        // 0..3
    const int tt = t & 255;
    const int lane = tt & 63;
    const int wv = tt >> 6;        // 0..3
    const int m = lane & 15;
    const int quad = lane >> 4;    // 0..3
    const int row0 = (blockIdx.x - SB) * 256 + sub * 64;
    const int arow = row0 + wv * 16 + m;
    const int rowc = (arow < NN) ? arow : (NN - 1);  // clamp; store guarded
    const float4* ap = (const float4*)(h + (size_t)rowc * KF + quad * 8);

    float4 a[16];
#pragma unroll
    for (int k = 0; k < 8; ++k) {
      a[2 * k] = ap[k * 8];
      a[2 * k + 1] = ap[k * 8 + 1];
    }
    __builtin_amdgcn_sched_barrier(0);  // all 16 A-loads issue first

    short8 af[8];
#pragma unroll
    for (int k = 0; k < 8; ++k) {
      const float4 a0 = a[2 * k];
      const float4 a1 = a[2 * k + 1];
      af[k][0] = (short)f2bf(a0.x); af[k][1] = (short)f2bf(a0.y);
      af[k][2] = (short)f2bf(a0.z); af[k][3] = (short)f2bf(a0.w);
      af[k][4] = (short)f2bf(a1.x); af[k][5] = (short)f2bf(a1.y);
      af[k][6] = (short)f2bf(a1.z); af[k][7] = (short)f2bf(a1.w);
    }
    __syncthreads();  // wt ready

    f32x4 acc[4];
#pragma unroll
    for (int i = 0; i < 4; ++i) acc[i] = (f32x4){0.f, 0.f, 0.f, 0.f};

    const short8* wp = (const short8*)wt;
#pragma unroll
    for (int k0i = 0; k0i < 8; ++k0i) {
      const short8* wk = wp + k0i * 256 + lane;
#pragma unroll
      for (int nt = 0; nt < 4; ++nt) {
        const short8 bf = wk[nt * 64];  // ds_read_b128, conflict-free
        acc[nt] = __builtin_amdgcn_mfma_f32_16x16x32_bf16(af[k0i], bf, acc[nt], 0, 0, 0);
      }
    }

    const int gm0 = row0 + wv * 16 + quad * 4;
    float nrm[4];
#pragma unroll
    for (int r = 0; r < 4; ++r) nrm[r] = (gm0 + r < NN) ? norm[gm0 + r] : 0.f;
#pragma unroll
    for (int nt = 0; nt < 4; ++nt) {
#pragma unroll
      for (int r = 0; r < 4; ++r) {
        const int gm = gm0 + r;
        if (gm < NN) hwb[(size_t)gm * MF + nt * 16 + m] = f2bf(acc[nt][r] * nrm[r]);
      }
    }
    return;
  }

  // ---- scatter branch: one read of src/dst, edges held in 16 VGPRs ----
  __shared__ int hh[NBK];  // local histogram
  __shared__ int bb[NBK];  // reserved base -> running cursor
  const int base = (int)blockIdx.x * EPB;
  unsigned int ev[EPB / 1024];
#pragma unroll
  for (int i = 0; i < EPB / 1024; ++i) {
    const int e = base + i * 1024 + t;
    ev[i] = (e < NE) ? (((unsigned)src[e] << 16) | (unsigned)dst[e])
                     : 0xFFFFFFFFu;  // sentinel (dst=0xFFFF impossible: d<50000)
  }
  for (int i = t; i < NBK; i += 1024) hh[i] = 0;
  __syncthreads();
#pragma unroll
  for (int i = 0; i < EPB / 1024; ++i)
    if (ev[i] != 0xFFFFFFFFu) atomicAdd(&hh[(ev[i] & 0xFFFFu) >> 6], 1);
  __syncthreads();
  for (int i = t; i < NBK; i += 1024) {
    const int c = hh[i];
    bb[i] = c ? atomicAdd(&gCur[i], c) : 0;  // chunk reservation
  }
  __syncthreads();
#pragma unroll
  for (int i = 0; i < EPB / 1024; ++i) {
    const unsigned v = ev[i];
    if (v != 0xFFFFFFFFu) {
      const int d = (int)(v & 0xFFFFu);
      const int bk = d >> 6;
      const int p = atomicAdd(&bb[bk], 1);
      if (p < CAP) {
        eidx[(size_t)bk * CAP + p] = (int)((v >> 16) << 6) | (d & 63);
      } else {  // statistically unreachable; kept for correctness
        const int o = atomicAdd(gOvf, 1);
        if (o < OVF_CAP) ovf[o] = v;
      }
    }
  }
}

// ---- Kernel 2: per-bucket counting sort (LDS) + gather ----
// Round-2 structure; single change: gather batch widened 8 -> 16 loads in
// flight (mean degree ~16 -> most nodes covered by one batch), norm hoisted.
__global__ __launch_bounds__(1024) void sort_gather(
    const int* __restrict__ gCur, const int* __restrict__ gOvf,
    const unsigned int* __restrict__ ovf, const int* __restrict__ eidx,
    const unsigned short* __restrict__ hwb, const float* __restrict__ norm,
    const float* __restrict__ bias, float* __restrict__ out) {
  __shared__ int hcnt[64];   // histogram -> node end (after scan)
  __shared__ int sBeg[64];   // node start (local)
  __shared__ int sCur[64];
  __shared__ int sE[CAP];
  const int t = threadIdx.x;
  const int g = blockIdx.x;
  int cnt = gCur[g];
  cnt = (cnt < CAP) ? cnt : CAP;  // excess (never happens) is in ovf list
  cnt = __builtin_amdgcn_readfirstlane(cnt);
  const int* ep = eidx + (size_t)g * CAP;
  if (t < 64) hcnt[t] = 0;
  __syncthreads();
  // hist pass; stash edge words in regs (cnt <= 1536 -> <= 2 per thread)
  int v0 = -1, v1 = -1;
  if (t < cnt) {
    v0 = ep[t];
    atomicAdd(&hcnt[v0 & 63], 1);
  }
  if (t + 1024 < cnt) {
    v1 = ep[t + 1024];
    atomicAdd(&hcnt[v1 & 63], 1);
  }
  __syncthreads();
  if (t < 64) {  // wave 0: exclusive scan of 64 counts
    const int v = hcnt[t];
    int incl = v;
#pragma unroll
    for (int off = 1; off < 64; off <<= 1) {
      const int uu = __shfl_up(incl, off, 64);
      if (t >= off) incl += uu;
    }
    sBeg[t] = incl - v;
    sCur[t] = incl - v;
    hcnt[t] = incl;  // end
  }
  __syncthreads();
  if (v0 >= 0) sE[atomicAdd(&sCur[v0 & 63], 1)] = v0 >> 6;
  if (v1 >= 0) sE[atomicAdd(&sCur[v1 & 63], 1)] = v1 >> 6;
  __syncthreads();

  const int lane = t & 63;
  const int wv = t >> 6;  // 0..15; wave handles nodes wv, wv+16, wv+32, wv+48
  const float bi = bias[lane];
  const int novf = __builtin_amdgcn_readfirstlane(*gOvf);  // 0 in practice
#pragma unroll
  for (int nl = wv; nl < 64; nl += 16) {
    const int vtx = (g << 6) + nl;
    if (vtx >= NN) continue;
    const float nv = norm[vtx];  // hoist off the epilogue critical path
    const int s0i = __builtin_amdgcn_readfirstlane(sBeg[nl]);
    const int e0i = __builtin_amdgcn_readfirstlane(hcnt[nl]);
    float acc = 0.f;
    int i = s0i;
    for (; i + 16 <= e0i; i += 16) {  // 16 row-loads in flight
      int ss[16];
#pragma unroll
      for (int j = 0; j < 16; ++j) ss[j] = sE[i + j];
      unsigned short xs[16];
#pragma unroll
      for (int j = 0; j < 16; ++j) xs[j] = hwb[(size_t)ss[j] * MF + lane];
      __builtin_amdgcn_sched_barrier(0);  // keep all 16 loads ahead of adds
      float p0 = 0.f, p1 = 0.f, p2 = 0.f, p3 = 0.f;
#pragma unroll
      for (int j = 0; j < 16; j += 4) {
        p0 += bf2f(xs[j]);
        p1 += bf2f(xs[j + 1]);
        p2 += bf2f(xs[j + 2]);
        p3 += bf2f(xs[j + 3]);
      }
      acc += (p0 + p1) + (p2 + p3);
    }
    for (; i + 8 <= e0i; i += 8) {  // 8-wide tail
      const int s0 = sE[i], s1 = sE[i + 1], s2 = sE[i + 2], s3 = sE[i + 3];
      const int s4 = sE[i + 4], s5 = sE[i + 5], s6 = sE[i + 6], s7 = sE[i + 7];
      const unsigned short x0 = hwb[(size_t)s0 * MF + lane];
      const unsigned short x1 = hwb[(size_t)s1 * MF + lane];
      const unsigned short x2 = hwb[(size_t)s2 * MF + lane];
      const unsigned short x3 = hwb[(size_t)s3 * MF + lane];
      const unsigned short x4 = hwb[(size_t)s4 * MF + lane];
      const unsigned short x5 = hwb[(size_t)s5 * MF + lane];
      const unsigned short x6 = hwb[(size_t)s6 * MF + lane];
      const unsigned short x7 = hwb[(size_t)s7 * MF + lane];
      acc += bf2f(x0); acc += bf2f(x1); acc += bf2f(x2); acc += bf2f(x3);
      acc += bf2f(x4); acc += bf2f(x5); acc += bf2f(x6); acc += bf2f(x7);
    }
    for (; i < e0i; ++i) acc += bf2f(hwb[(size_t)sE[i] * MF + lane]);
    if (novf > 0) {  // cold path, wave-uniform skip
      const int nn = (novf < OVF_CAP) ? novf : OVF_CAP;
      for (int ii = 0; ii < nn; ++ii) {
        const unsigned v = ovf[ii];
        if ((int)(v & 0xFFFFu) == vtx)
          acc += bf2f(hwb[(size_t)(v >> 16) * MF + lane]);
      }
    }
    const float o = acc * nv + bi;
    out[(size_t)vtx * MF + lane] = fmaxf(o, 0.f);
  }
}

extern "C" void kernel_launch(void* const* d_in, const int* in_sizes, int n_in,
                              void* d_out, int out_size, void* d_ws, size_t ws_size,
                              hipStream_t stream) {
  const float* h = (const float*)d_in[0];
  const float* norm = (const float*)d_in[1];
  const float* W = (const float*)d_in[2];
  const float* bias = (const float*)d_in[3];
  const int* src = (const int*)d_in[4];
  const int* dst = (const int*)d_in[5];
  float* out = (float*)d_out;

  unsigned short* hwb = (unsigned short*)d_ws;            // NN*MF bf16 (6.4 MB)
  int* gCur = (int*)(hwb + (size_t)NN * MF);              // NBK bucket cursors
  int* gOvf = gCur + NBK;                                 // overflow counter
  unsigned int* ovf = (unsigned int*)(gOvf + 1);          // OVF_CAP entries
  int* eidx = (int*)(ovf + OVF_CAP);                      // NBK*CAP (4.8 MB)
  const size_t need = (size_t)NN * MF * 2 +
                      ((size_t)NBK + 1 + OVF_CAP + (size_t)NBK * CAP) * 4;
  if (ws_size < need) return;

  hipMemsetAsync(gCur, 0, (NBK + 1) * sizeof(int), stream);  // 3 KB
  scatter_gemm<<<SB + GEMMB, 1024, 0, stream>>>(src, dst, gCur, gOvf, ovf,
                                                eidx, h, W, norm, hwb);
  sort_gather<<<NBK, 1024, 0, stream>>>(gCur, gOvf, ovf, eidx, hwb, norm, bias,
                                        out);
}

// Round 7
// 130.526 us; speedup vs baseline: 1.1705x; 1.0318x over previous
//
#include <hip/hip_runtime.h>

#define NN 50000
#define NE 800000
#define KF 256
#define MF 64

#define NBK 782      // node buckets of 64: ceil(50000/64)
#define SB 60        // scatter blocks (49 -> 60: shorter scatter tail)
#define EPB 14336    // edges per scatter block (60*14336 >= 800000)
#define EPT 14       // edges per thread
#define CAP 1536     // fixed slots per bucket (mean 1024 + ~16 sigma)
#define GEMMB 196    // gemm blocks: each does 256 rows; grid = 256 total
#define OVF_CAP 4096 // overflow list capacity (never used in practice)

typedef __attribute__((ext_vector_type(8))) short short8;
typedef __attribute__((ext_vector_type(4))) float f32x4;

static __device__ __forceinline__ unsigned short f2bf(float x) {
  unsigned int u = __float_as_uint(x);
  u += 0x7FFF + ((u >> 16) & 1);  // round-nearest-even
  return (unsigned short)(u >> 16);
}
static __device__ __forceinline__ float bf2f(unsigned short u) {
  return __uint_as_float(((unsigned int)u) << 16);
}

// ---- Kernel 1: fused edge scatter (blocks 0..SB-1) + MFMA GEMM (SB..) ----
// Structure identical to the round-2/6 passing version; only SB/EPT changed
// and a 128B zero-row written at hwb[NN] (k2's padding target).
__global__ __launch_bounds__(1024) void scatter_gemm(
    const int* __restrict__ src, const int* __restrict__ dst,
    int* __restrict__ gCur, int* __restrict__ gOvf,
    unsigned int* __restrict__ ovf, int* __restrict__ eidx,
    const float* __restrict__ h, const float* __restrict__ W,
    const float* __restrict__ norm, unsigned short* __restrict__ hwb) {
  const int t = threadIdx.x;

  if (blockIdx.x >= SB) {  // ---- GEMM branch: 4 x 64-row tiles ----
    __shared__ unsigned short wt[16384];  // 32 KB B-fragment table
    if (blockIdx.x == SB && t < 64) hwb[(size_t)NN * MF + t] = 0;  // zero row
    // prepack W -> LDS (layout: f = k0i*256 + nt*64 + quad*16 + m)
    for (int f = t; f < 2048; f += 1024) {
      const int m = f & 15;
      const int quad = (f >> 4) & 3;
      const int nt = (f >> 6) & 3;
      const int k0i = f >> 8;
      const int n = nt * 16 + m;
      const int kb = k0i * 32 + quad * 8;
      short8 p;
#pragma unroll
      for (int j = 0; j < 8; ++j) p[j] = (short)f2bf(W[(kb + j) * MF + n]);
      *(short8*)(wt + (size_t)f * 8) = p;
    }

    const int sub = t >> 8;        // 0..3
    const int tt = t & 255;
    const int lane = tt & 63;
    const int wv = tt >> 6;        // 0..3
    const int m = lane & 15;
    const int quad = lane >> 4;    // 0..3
    const int row0 = (blockIdx.x - SB) * 256 + sub * 64;
    const int arow = row0 + wv * 16 + m;
    const int rowc = (arow < NN) ? arow : (NN - 1);  // clamp; store guarded
    const float4* ap = (const float4*)(h + (size_t)rowc * KF + quad * 8);

    float4 a[16];
#pragma unroll
    for (int k = 0; k < 8; ++k) {
      a[2 * k] = ap[k * 8];
      a[2 * k + 1] = ap[k * 8 + 1];
    }
    __builtin_amdgcn_sched_barrier(0);  // all 16 A-loads issue first

    short8 af[8];
#pragma unroll
    for (int k = 0; k < 8; ++k) {
      const float4 a0 = a[2 * k];
      const float4 a1 = a[2 * k + 1];
      af[k][0] = (short)f2bf(a0.x); af[k][1] = (short)f2bf(a0.y);
      af[k][2] = (short)f2bf(a0.z); af[k][3] = (short)f2bf(a0.w);
      af[k][4] = (short)f2bf(a1.x); af[k][5] = (short)f2bf(a1.y);
      af[k][6] = (short)f2bf(a1.z); af[k][7] = (short)f2bf(a1.w);
    }
    __syncthreads();  // wt ready

    f32x4 acc[4];
#pragma unroll
    for (int i = 0; i < 4; ++i) acc[i] = (f32x4){0.f, 0.f, 0.f, 0.f};

    const short8* wp = (const short8*)wt;
#pragma unroll
    for (int k0i = 0; k0i < 8; ++k0i) {
      const short8* wk = wp + k0i * 256 + lane;
#pragma unroll
      for (int nt = 0; nt < 4; ++nt) {
        const short8 bf = wk[nt * 64];  // ds_read_b128, conflict-free
        acc[nt] = __builtin_amdgcn_mfma_f32_16x16x32_bf16(af[k0i], bf, acc[nt], 0, 0, 0);
      }
    }

    const int gm0 = row0 + wv * 16 + quad * 4;
    float nrm[4];
#pragma unroll
    for (int r = 0; r < 4; ++r) nrm[r] = (gm0 + r < NN) ? norm[gm0 + r] : 0.f;
#pragma unroll
    for (int nt = 0; nt < 4; ++nt) {
#pragma unroll
      for (int r = 0; r < 4; ++r) {
        const int gm = gm0 + r;
        if (gm < NN) hwb[(size_t)gm * MF + nt * 16 + m] = f2bf(acc[nt][r] * nrm[r]);
      }
    }
    return;
  }

  // ---- scatter branch: one read of src/dst, edges held in 14 VGPRs ----
  __shared__ int hh[NBK];  // local histogram
  __shared__ int bb[NBK];  // reserved base -> running cursor
  const int base = (int)blockIdx.x * EPB;
  unsigned int ev[EPT];
#pragma unroll
  for (int i = 0; i < EPT; ++i) {
    const int e = base + i * 1024 + t;
    ev[i] = (e < NE) ? (((unsigned)src[e] << 16) | (unsigned)dst[e])
                     : 0xFFFFFFFFu;  // sentinel (dst=0xFFFF impossible: d<50000)
  }
  for (int i = t; i < NBK; i += 1024) hh[i] = 0;
  __syncthreads();
#pragma unroll
  for (int i = 0; i < EPT; ++i)
    if (ev[i] != 0xFFFFFFFFu) atomicAdd(&hh[(ev[i] & 0xFFFFu) >> 6], 1);
  __syncthreads();
  for (int i = t; i < NBK; i += 1024) {
    const int c = hh[i];
    bb[i] = c ? atomicAdd(&gCur[i], c) : 0;  // chunk reservation
  }
  __syncthreads();
#pragma unroll
  for (int i = 0; i < EPT; ++i) {
    const unsigned v = ev[i];
    if (v != 0xFFFFFFFFu) {
      const int d = (int)(v & 0xFFFFu);
      const int bk = d >> 6;
      const int p = atomicAdd(&bb[bk], 1);
      if (p < CAP) {
        eidx[(size_t)bk * CAP + p] = (int)((v >> 16) << 6) | (d & 63);
      } else {  // statistically unreachable; kept for correctness
        const int o = atomicAdd(gOvf, 1);
        if (o < OVF_CAP) ovf[o] = v;
      }
    }
  }
}

// ---- Kernel 2: per-bucket counting sort (LDS) + gather ----
// Round-2 structure; change: each node's segment padded to a multiple of 8
// with dummy index NN (zero row) -> gather has NO serial scalar tail.
__global__ __launch_bounds__(1024) void sort_gather(
    const int* __restrict__ gCur, const int* __restrict__ gOvf,
    const unsigned int* __restrict__ ovf, const int* __restrict__ eidx,
    const unsigned short* __restrict__ hwb, const float* __restrict__ norm,
    const float* __restrict__ bias, float* __restrict__ out) {
  __shared__ int hcnt[64];   // histogram counts -> real end (after scan)
  __shared__ int sBeg[64];   // node start (padded layout)
  __shared__ int sCur[64];
  __shared__ int pEnd[64];   // padded end (multiple-of-8 segment)
  __shared__ int sE[2048];   // padded capacity: 1536 + 64*7 = 1984 <= 2048
  const int t = threadIdx.x;
  const int g = blockIdx.x;
  int cnt = gCur[g];
  cnt = (cnt < CAP) ? cnt : CAP;  // excess (never happens) is in ovf list
  cnt = __builtin_amdgcn_readfirstlane(cnt);
  const int* ep = eidx + (size_t)g * CAP;
  if (t < 64) hcnt[t] = 0;
  __syncthreads();
  // hist pass; stash edge words in regs (cnt <= 1536 -> <= 2 per thread)
  int v0 = -1, v1 = -1;
  if (t < cnt) {
    v0 = ep[t];
    atomicAdd(&hcnt[v0 & 63], 1);
  }
  if (t + 1024 < cnt) {
    v1 = ep[t + 1024];
    atomicAdd(&hcnt[v1 & 63], 1);
  }
  __syncthreads();
  if (t < 64) {  // wave 0: exclusive scan of PADDED counts
    const int v = hcnt[t];
    const int pc = (v + 7) & ~7;  // pad each node to x8
    int incl = pc;
#pragma unroll
    for (int off = 1; off < 64; off <<= 1) {
      const int uu = __shfl_up(incl, off, 64);
      if (t >= off) incl += uu;
    }
    const int beg = incl - pc;
    sBeg[t] = beg;
    sCur[t] = beg;
    hcnt[t] = beg + v;   // real end = dummy-fill start
    pEnd[t] = beg + pc;  // padded end
  }
  __syncthreads();
  // placement into [beg, realEnd) + dummy fill [realEnd, pEnd): disjoint
  if (v0 >= 0) sE[atomicAdd(&sCur[v0 & 63], 1)] = v0 >> 6;
  if (v1 >= 0) sE[atomicAdd(&sCur[v1 & 63], 1)] = v1 >> 6;
  if (t < 64) {
    for (int j = hcnt[t]; j < pEnd[t]; ++j) sE[j] = NN;  // <= 7 dummies
  }
  __syncthreads();

  const int lane = t & 63;
  const int wv = t >> 6;  // 0..15; wave handles nodes wv, wv+16, wv+32, wv+48
  const float bi = bias[lane];
  const int novf = __builtin_amdgcn_readfirstlane(*gOvf);  // 0 in practice
#pragma unroll
  for (int nl = wv; nl < 64; nl += 16) {
    const int vtx = (g << 6) + nl;
    if (vtx >= NN) continue;
    const float nv = norm[vtx];
    const int s0i = __builtin_amdgcn_readfirstlane(sBeg[nl]);
    const int e0i = __builtin_amdgcn_readfirstlane(pEnd[nl]);  // x8 length
    float acc = 0.f;
    int i = s0i;
    for (; i + 16 <= e0i; i += 16) {  // 16 row-loads in flight
      int ss[16];
#pragma unroll
      for (int j = 0; j < 16; ++j) ss[j] = sE[i + j];
      unsigned short xs[16];
#pragma unroll
      for (int j = 0; j < 16; ++j) xs[j] = hwb[(size_t)ss[j] * MF + lane];
      __builtin_amdgcn_sched_barrier(0);
      float p0 = 0.f, p1 = 0.f, p2 = 0.f, p3 = 0.f;
#pragma unroll
      for (int j = 0; j < 16; j += 4) {
        p0 += bf2f(xs[j]);
        p1 += bf2f(xs[j + 1]);
        p2 += bf2f(xs[j + 2]);
        p3 += bf2f(xs[j + 3]);
      }
      acc += (p0 + p1) + (p2 + p3);
    }
    if (i < e0i) {  // exactly one 8-wide step (padded length is x8)
      const int s0 = sE[i], s1 = sE[i + 1], s2 = sE[i + 2], s3 = sE[i + 3];
      const int s4 = sE[i + 4], s5 = sE[i + 5], s6 = sE[i + 6], s7 = sE[i + 7];
      const unsigned short x0 = hwb[(size_t)s0 * MF + lane];
      const unsigned short x1 = hwb[(size_t)s1 * MF + lane];
      const unsigned short x2 = hwb[(size_t)s2 * MF + lane];
      const unsigned short x3 = hwb[(size_t)s3 * MF + lane];
      const unsigned short x4 = hwb[(size_t)s4 * MF + lane];
      const unsigned short x5 = hwb[(size_t)s5 * MF + lane];
      const unsigned short x6 = hwb[(size_t)s6 * MF + lane];
      const unsigned short x7 = hwb[(size_t)s7 * MF + lane];
      acc += bf2f(x0); acc += bf2f(x1); acc += bf2f(x2); acc += bf2f(x3);
      acc += bf2f(x4); acc += bf2f(x5); acc += bf2f(x6); acc += bf2f(x7);
    }
    if (novf > 0) {  // cold path, wave-uniform skip
      const int nn = (novf < OVF_CAP) ? novf : OVF_CAP;
      for (int ii = 0; ii < nn; ++ii) {
        const unsigned v = ovf[ii];
        if ((int)(v & 0xFFFFu) == vtx)
          acc += bf2f(hwb[(size_t)(v >> 16) * MF + lane]);
      }
    }
    const float o = acc * nv + bi;
    out[(size_t)vtx * MF + lane] = fmaxf(o, 0.f);
  }
}

extern "C" void kernel_launch(void* const* d_in, const int* in_sizes, int n_in,
                              void* d_out, int out_size, void* d_ws, size_t ws_size,
                              hipStream_t stream) {
  const float* h = (const float*)d_in[0];
  const float* norm = (const float*)d_in[1];
  const float* W = (const float*)d_in[2];
  const float* bias = (const float*)d_in[3];
  const int* src = (const int*)d_in[4];
  const int* dst = (const int*)d_in[5];
  float* out = (float*)d_out;

  unsigned short* hwb = (unsigned short*)d_ws;            // (NN+1)*MF bf16
  int* gCur = (int*)(hwb + (size_t)(NN + 1) * MF);        // NBK bucket cursors
  int* gOvf = gCur + NBK;                                 // overflow counter
  unsigned int* ovf = (unsigned int*)(gOvf + 1);          // OVF_CAP entries
  int* eidx = (int*)(ovf + OVF_CAP);                      // NBK*CAP (4.8 MB)
  const size_t need = (size_t)(NN + 1) * MF * 2 +
                      ((size_t)NBK + 1 + OVF_CAP + (size_t)NBK * CAP) * 4;
  if (ws_size < need) return;

  hipMemsetAsync(gCur, 0, (NBK + 1) * sizeof(int), stream);  // 3 KB
  scatter_gemm<<<SB + GEMMB, 1024, 0, stream>>>(src, dst, gCur, gOvf, ovf,
                                                eidx, h, W, norm, hwb);
  sort_gather<<<NBK, 1024, 0, stream>>>(gCur, gOvf, ovf, eidx, hwb, norm, bias,
                                        out);
}